// Round 1
// baseline (556.322 us; speedup 1.0000x reference)
//
#include <hip/hip_runtime.h>
#include <hip/hip_bf16.h>

// Problem constants
constexpr int B = 8, N = 4096, D = 768;
constexpr int H = 12, K = 16, U = 4, V = 64, L = 23, PAD = 11;
constexpr int CQ = 192;           // q channels [0,192)
constexpr int CK = 64;            // k channels [192,256)
constexpr int CV = 256;           // v channels [256,512)
constexpr int CT = 512;           // total channels
constexpr int CV0 = CQ + CK;      // 256
constexpr float EPS = 1e-5f;

// ---------------------------------------------------------------------------
// K1: fused projection GEMM  P[b][c][n] = sum_d W[c][d] * x[b][n][d]
//     W rows: c<192 -> Wq[c], c<256 -> Wk[c-192], else Wv[c-256]
//     64x64 tile, 256 threads, 4x4 microtile, k-chunk 16
// ---------------------------------------------------------------------------
__global__ __launch_bounds__(256) void k_proj(
    const float* __restrict__ x,
    const float* __restrict__ Wq, const float* __restrict__ Wk,
    const float* __restrict__ Wv, float* __restrict__ P)
{
    __shared__ float Wt[16][68];   // [d][c]
    __shared__ float Xt[16][68];   // [d][n]
    const int b  = blockIdx.z;
    const int bc = blockIdx.y * 64;
    const int bn = blockIdx.x * 64;
    const int tid = threadIdx.x;
    const int tx = tid & 15, ty = tid >> 4;
    const int lc = tid >> 2;          // 0..63  (tile row for loads)
    const int ld = (tid & 3) * 4;     // 0,4,8,12

    const int c = bc + lc;
    const float* wrow;
    if (c < CQ)            wrow = Wq + (size_t)c * D;
    else if (c < CQ + CK)  wrow = Wk + (size_t)(c - CQ) * D;
    else                   wrow = Wv + (size_t)(c - CV0) * D;
    const float* xrow = x + ((size_t)b * N + (bn + lc)) * D;

    float acc[4][4] = {};
    for (int d0 = 0; d0 < D; d0 += 16) {
        float4 wv = *(const float4*)(wrow + d0 + ld);
        float4 xv = *(const float4*)(xrow + d0 + ld);
        __syncthreads();
        Wt[ld+0][lc] = wv.x; Wt[ld+1][lc] = wv.y; Wt[ld+2][lc] = wv.z; Wt[ld+3][lc] = wv.w;
        Xt[ld+0][lc] = xv.x; Xt[ld+1][lc] = xv.y; Xt[ld+2][lc] = xv.z; Xt[ld+3][lc] = xv.w;
        __syncthreads();
        #pragma unroll
        for (int kk = 0; kk < 16; ++kk) {
            float4 a  = *(const float4*)&Wt[kk][ty * 4];
            float4 bb = *(const float4*)&Xt[kk][tx * 4];
            acc[0][0] += a.x*bb.x; acc[0][1] += a.x*bb.y; acc[0][2] += a.x*bb.z; acc[0][3] += a.x*bb.w;
            acc[1][0] += a.y*bb.x; acc[1][1] += a.y*bb.y; acc[1][2] += a.y*bb.z; acc[1][3] += a.y*bb.w;
            acc[2][0] += a.z*bb.x; acc[2][1] += a.z*bb.y; acc[2][2] += a.z*bb.z; acc[2][3] += a.z*bb.w;
            acc[3][0] += a.w*bb.x; acc[3][1] += a.w*bb.y; acc[3][2] += a.w*bb.z; acc[3][3] += a.w*bb.w;
        }
    }
    float* Pb = P + ((size_t)b * CT + bc) * N + bn;
    #pragma unroll
    for (int i = 0; i < 4; ++i) {
        float4 o = {acc[i][0], acc[i][1], acc[i][2], acc[i][3]};
        *(float4*)(Pb + (size_t)(ty * 4 + i) * N + tx * 4) = o;
    }
}

// ---------------------------------------------------------------------------
// K2: BN stats -> per-channel scale/shift (q and v channels only)
// ---------------------------------------------------------------------------
__global__ __launch_bounds__(256) void k_bnstats(
    const float* __restrict__ P,
    const float* __restrict__ gq, const float* __restrict__ bq,
    const float* __restrict__ gv, const float* __restrict__ bv,
    float* __restrict__ sArr, float* __restrict__ tArr)
{
    const int ci = blockIdx.x;              // 0..447
    const int c  = (ci < CQ) ? ci : ci + CK;
    float g, be;
    if (ci < CQ) { g = gq[ci];      be = bq[ci]; }
    else         { g = gv[ci - CQ]; be = bv[ci - CQ]; }

    const int tid = threadIdx.x;
    float s = 0.f, s2 = 0.f;
    for (int b = 0; b < B; ++b) {
        const float* row = P + ((size_t)b * CT + c) * N;
        #pragma unroll
        for (int i = 0; i < 4; ++i) {
            float4 v = *(const float4*)(row + (i * 256 + tid) * 4);
            s  += v.x + v.y + v.z + v.w;
            s2 += v.x*v.x + v.y*v.y + v.z*v.z + v.w*v.w;
        }
    }
    #pragma unroll
    for (int off = 32; off; off >>= 1) {
        s  += __shfl_xor(s, off);
        s2 += __shfl_xor(s2, off);
    }
    __shared__ float ls[4], ls2[4];
    if ((tid & 63) == 0) { ls[tid >> 6] = s; ls2[tid >> 6] = s2; }
    __syncthreads();
    if (tid == 0) {
        float S = ls[0] + ls[1] + ls[2] + ls[3];
        float S2 = ls2[0] + ls2[1] + ls2[2] + ls2[3];
        const float invM = 1.0f / (float)(B * N);
        float mean = S * invM;
        float var  = S2 * invM - mean * mean;
        float sc   = g / sqrtf(var + EPS);
        sArr[c] = sc;
        tArr[c] = be - mean * sc;
    }
}

// ---------------------------------------------------------------------------
// K3: apply BN affine in place (q and v channels)
// ---------------------------------------------------------------------------
__global__ __launch_bounds__(256) void k_bnapply(
    float* __restrict__ P, const float* __restrict__ sArr, const float* __restrict__ tArr)
{
    const int ci = blockIdx.x;
    const int c  = (ci < CQ) ? ci : ci + CK;
    const int b  = blockIdx.y;
    const float sc = sArr[c], tt = tArr[c];
    float* row = P + ((size_t)b * CT + c) * N;
    const int tid = threadIdx.x;
    #pragma unroll
    for (int i = 0; i < 4; ++i) {
        float4 v = *(float4*)(row + (i * 256 + tid) * 4);
        v.x = v.x * sc + tt; v.y = v.y * sc + tt;
        v.z = v.z * sc + tt; v.w = v.w * sc + tt;
        *(float4*)(row + (i * 256 + tid) * 4) = v;
    }
}

// ---------------------------------------------------------------------------
// K4: softmax over n for each k-channel row, in place
// ---------------------------------------------------------------------------
__global__ __launch_bounds__(256) void k_softmax(float* __restrict__ P)
{
    const int b = blockIdx.y, c = CQ + blockIdx.x;
    float* row = P + ((size_t)b * CT + c) * N;
    const int tid = threadIdx.x;
    float v[16];
    float m = -3.4e38f;
    #pragma unroll
    for (int i = 0; i < 4; ++i) {
        float4 t = *(const float4*)(row + (i * 256 + tid) * 4);
        v[i*4+0] = t.x; v[i*4+1] = t.y; v[i*4+2] = t.z; v[i*4+3] = t.w;
        m = fmaxf(m, fmaxf(fmaxf(t.x, t.y), fmaxf(t.z, t.w)));
    }
    #pragma unroll
    for (int off = 32; off; off >>= 1) m = fmaxf(m, __shfl_xor(m, off));
    __shared__ float rA[4], rB[4];
    if ((tid & 63) == 0) rA[tid >> 6] = m;
    __syncthreads();
    m = fmaxf(fmaxf(rA[0], rA[1]), fmaxf(rA[2], rA[3]));
    float s = 0.f;
    #pragma unroll
    for (int i = 0; i < 16; ++i) { v[i] = __expf(v[i] - m); s += v[i]; }
    #pragma unroll
    for (int off = 32; off; off >>= 1) s += __shfl_xor(s, off);
    if ((tid & 63) == 0) rB[tid >> 6] = s;
    __syncthreads();
    s = rB[0] + rB[1] + rB[2] + rB[3];
    const float inv = 1.f / s;
    #pragma unroll
    for (int i = 0; i < 4; ++i) {
        float4 t = {v[i*4+0]*inv, v[i*4+1]*inv, v[i*4+2]*inv, v[i*4+3]*inv};
        *(float4*)(row + (i * 256 + tid) * 4) = t;
    }
}

// ---------------------------------------------------------------------------
// K5: zero lam_c, then lam_c[b][k][v] += sum_{u,n} ksm[b][k*U+u][n]*vbn[b][v*U+u][n]
// ---------------------------------------------------------------------------
__global__ void k_zero(float* __restrict__ p)
{
    ((float4*)p)[blockIdx.x * 256 + threadIdx.x] = float4{0.f, 0.f, 0.f, 0.f};
}

__global__ __launch_bounds__(256) void k_lamc(
    const float* __restrict__ P, float* __restrict__ lamC)
{
    __shared__ float Kt[128][20];   // [n][k]
    __shared__ float Vt[128][68];   // [n][v]
    const int b = blockIdx.z, u = blockIdx.y;
    const int chunk0 = blockIdx.x * 512;
    const int tid = threadIdx.x;
    const int vv = tid & 63, kg = tid >> 6;
    float acc[4] = {0.f, 0.f, 0.f, 0.f};

    for (int sc = 0; sc < 4; ++sc) {
        const int nbase = chunk0 + sc * 128;
        __syncthreads();
        for (int idx = tid; idx < 16 * 128; idx += 256) {
            int kk = idx >> 7, n = idx & 127;
            Kt[n][kk] = P[((size_t)b * CT + CQ + kk * U + u) * N + nbase + n];
        }
        for (int idx = tid; idx < 64 * 128; idx += 256) {
            int vvv = idx >> 7, n = idx & 127;
            Vt[n][vvv] = P[((size_t)b * CT + CV0 + vvv * U + u) * N + nbase + n];
        }
        __syncthreads();
        #pragma unroll 4
        for (int n = 0; n < 128; ++n) {
            float4 kv = *(const float4*)&Kt[n][kg * 4];
            float vx = Vt[n][vv];
            acc[0] += kv.x * vx; acc[1] += kv.y * vx;
            acc[2] += kv.z * vx; acc[3] += kv.w * vx;
        }
    }
    #pragma unroll
    for (int j = 0; j < 4; ++j)
        atomicAdd(&lamC[((size_t)b * K + kg * 4 + j) * V + vv], acc[j]);
}

// ---------------------------------------------------------------------------
// K6: fused position-lambda conv + output
//   Y[b][n][h*64+v] = sum_k q[b][h*16+k][n] * ( lam_c[b][k][v] + lam_p[k][v][n] )
//   lam_p[k][v][n]  = sum_{u,l} vbn[b][v*4+u][n-11+l] * rel[k][u][l]
//   block = (b, 16-position tile); thread = (v-group of 4, n); 16x4 lam in regs
// ---------------------------------------------------------------------------
__global__ __launch_bounds__(256) void k_out(
    const float* __restrict__ P, const float* __restrict__ rel,
    const float* __restrict__ lamC, float* __restrict__ Y)
{
    __shared__ float vseg[4][38][64];     // [u][np][v]
    __shared__ float Wl[92][16];          // [(u*23+l)][k]
    __shared__ float qtile[12][16][16];   // [h][nn][k]

    const int b = blockIdx.y;
    const int n0 = blockIdx.x * 16;
    const int tid = threadIdx.x;

    // stage v halo: thread = v-channel (c = 256 + tid); coalesced-over-n per row
    {
        const int u = tid & 3, vv = tid >> 2;
        const float* row = P + ((size_t)b * CT + CV0 + tid) * N;
        for (int np = 0; np < 38; ++np) {
            const int n = n0 - PAD + np;
            vseg[u][np][vv] = (n >= 0 && n < N) ? row[n] : 0.f;
        }
    }
    // stage q tile (threads 0..191), layout [h][nn][k]
    if (tid < CQ) {
        const int h = tid >> 4, k = tid & 15;
        const float* row = P + ((size_t)b * CT + tid) * N + n0;
        for (int nn = 0; nn < 16; ++nn) qtile[h][nn][k] = row[nn];
    }
    // stage rel weights transposed: Wl[u*23+l][k]
    for (int idx = tid; idx < K * U * L; idx += 256) {
        const int k = idx / (U * L), r = idx % (U * L);
        Wl[r][k] = rel[idx];
    }
    __syncthreads();

    const int vv4 = tid & 15;   // v = vv4*4 + vi
    const int nn  = tid >> 4;   // 0..15
    float lam[16][4];
    const float* lamCb = lamC + (size_t)b * K * V;
    #pragma unroll
    for (int k = 0; k < 16; ++k) {
        float4 lc = *(const float4*)(lamCb + k * V + vv4 * 4);
        lam[k][0] = lc.x; lam[k][1] = lc.y; lam[k][2] = lc.z; lam[k][3] = lc.w;
    }

    #pragma unroll 1
    for (int u = 0; u < 4; ++u) {
        #pragma unroll
        for (int l = 0; l < 23; ++l) {
            float4 vx = *(const float4*)&vseg[u][nn + l][vv4 * 4];
            const float vx4[4] = {vx.x, vx.y, vx.z, vx.w};
            #pragma unroll
            for (int kg = 0; kg < 4; ++kg) {
                float4 w = *(const float4*)&Wl[u * 23 + l][kg * 4];
                const float w4[4] = {w.x, w.y, w.z, w.w};
                #pragma unroll
                for (int j = 0; j < 4; ++j)
                    #pragma unroll
                    for (int vi = 0; vi < 4; ++vi)
                        lam[kg * 4 + j][vi] += w4[j] * vx4[vi];
            }
        }
    }

    const int n = n0 + nn;
    float* Yrow = Y + ((size_t)b * N + n) * (H * V);
    for (int h = 0; h < H; ++h) {
        float y[4] = {0.f, 0.f, 0.f, 0.f};
        #pragma unroll
        for (int kg = 0; kg < 4; ++kg) {
            float4 q4 = *(const float4*)&qtile[h][nn][kg * 4];
            const float qa[4] = {q4.x, q4.y, q4.z, q4.w};
            #pragma unroll
            for (int j = 0; j < 4; ++j)
                #pragma unroll
                for (int vi = 0; vi < 4; ++vi)
                    y[vi] += qa[j] * lam[kg * 4 + j][vi];
        }
        float4 o = {y[0], y[1], y[2], y[3]};
        *(float4*)(Yrow + h * 64 + vv4 * 4) = o;
    }
}

// ---------------------------------------------------------------------------
extern "C" void kernel_launch(void* const* d_in, const int* in_sizes, int n_in,
                              void* d_out, int out_size, void* d_ws, size_t ws_size,
                              hipStream_t stream)
{
    const float* x   = (const float*)d_in[0];
    const float* Wq  = (const float*)d_in[1];
    const float* Wk  = (const float*)d_in[2];
    const float* Wv  = (const float*)d_in[3];
    const float* gq  = (const float*)d_in[4];
    const float* bq  = (const float*)d_in[5];
    const float* gv  = (const float*)d_in[6];
    const float* bv  = (const float*)d_in[7];
    const float* rel = (const float*)d_in[8];
    float* Y = (float*)d_out;

    float* P    = (float*)d_ws;                       // B*CT*N floats (64 MiB)
    float* sArr = P + (size_t)B * CT * N;             // CT
    float* tArr = sArr + CT;                          // CT
    float* lamC = tArr + CT;                          // B*K*V = 8192

    k_proj   <<<dim3(N / 64, CT / 64, B), 256, 0, stream>>>(x, Wq, Wk, Wv, P);
    k_bnstats<<<dim3(CQ + CV), 256, 0, stream>>>(P, gq, bq, gv, bv, sArr, tArr);
    k_bnapply<<<dim3(CQ + CV, B), 256, 0, stream>>>(P, sArr, tArr);
    k_softmax<<<dim3(CK, B), 256, 0, stream>>>(P);
    k_zero   <<<dim3(8), 256, 0, stream>>>(lamC);
    k_lamc   <<<dim3(N / 512, U, B), 256, 0, stream>>>(P, lamC);
    k_out    <<<dim3(N / 16, B), 256, 0, stream>>>(P, rel, lamC, Y);
}

// Round 2
// 292.825 us; speedup vs baseline: 1.8998x; 1.8998x over previous
//
#include <hip/hip_runtime.h>
#include <hip/hip_bf16.h>

// Problem constants
constexpr int B = 8, N = 4096, D = 768;
constexpr int H = 12, K = 16, U = 4, V = 64, L = 23, PAD = 11;
constexpr int CQ = 192;           // q channels [0,192)
constexpr int CK = 64;            // k channels [192,256)
constexpr int CV = 256;           // v channels [256,512)
constexpr int CT = 512;           // total channels
constexpr int CV0 = CQ + CK;      // 256
constexpr float EPS = 1e-5f;

typedef _Float16 f16x8 __attribute__((ext_vector_type(8)));
typedef float    f32x4 __attribute__((ext_vector_type(4)));

// ---------------------------------------------------------------------------
// K1: fused projection GEMM on MFMA (f16 inputs, fp32 accum)
//   P[b][c][n] = sum_d W[c][d] * x[b][n][d]
//   128x128 tile, BK=32, 4 waves, each wave 64x64 (4x4 frags of 16x16x32).
//   fp32->f16 convert fused into reg-staged LDS writes.
//   LDS [128][32] f16 rows (64B); 16B-slot XOR swizzle to kill ds_read
//   column conflicts (slot ^ (row&3) ^ ((row>>2)&3)).
// ---------------------------------------------------------------------------
__device__ __forceinline__ int lds_off(int row, int slot) {
    int p = slot ^ (row & 3) ^ ((row >> 2) & 3);
    return row * 64 + p * 16;          // byte offset
}

__device__ __forceinline__ f16x8 cvt8(const float* __restrict__ p) {
    float4 a = *(const float4*)p;
    float4 b = *(const float4*)(p + 4);
    f16x8 r;
    r[0] = (_Float16)a.x; r[1] = (_Float16)a.y; r[2] = (_Float16)a.z; r[3] = (_Float16)a.w;
    r[4] = (_Float16)b.x; r[5] = (_Float16)b.y; r[6] = (_Float16)b.z; r[7] = (_Float16)b.w;
    return r;
}

__global__ __launch_bounds__(256) void k_proj(
    const float* __restrict__ x,
    const float* __restrict__ Wq, const float* __restrict__ Wk,
    const float* __restrict__ Wv, float* __restrict__ P)
{
    __shared__ _Float16 As[128 * 32];   // [row=c][col=d] swizzled
    __shared__ _Float16 Bs[128 * 32];   // [row=n][col=d] swizzled
    const int b  = blockIdx.z;
    const int bc = blockIdx.y * 128;
    const int bn = blockIdx.x * 128;
    const int tid  = threadIdx.x;
    const int lane = tid & 63;
    const int wave = tid >> 6;
    const int wr = wave >> 1, wc = wave & 1;

    // staging: thread t owns row t>>1, 16 f16 cols starting at (t&1)*16
    const int srow  = tid >> 1;
    const int scolg = (tid & 1) * 16;
    const int s0    = (tid & 1) * 2;     // first 16B slot (0 or 2)
    const int c = bc + srow;
    const float* wrow;
    if (c < CQ)       wrow = Wq + (size_t)c * D;
    else if (c < CV0) wrow = Wk + (size_t)(c - CQ) * D;
    else              wrow = Wv + (size_t)(c - CV0) * D;
    const float* xrow = x + ((size_t)b * N + bn + srow) * D;

    const int fr = lane & 15;   // fragment row / col
    const int sl = lane >> 4;   // k-slot 0..3

    f32x4 acc[4][4] = {};

    for (int kt = 0; kt < D; kt += 32) {
        f16x8 wa0 = cvt8(wrow + kt + scolg);
        f16x8 wa1 = cvt8(wrow + kt + scolg + 8);
        f16x8 xa0 = cvt8(xrow + kt + scolg);
        f16x8 xa1 = cvt8(xrow + kt + scolg + 8);
        __syncthreads();
        *(f16x8*)((char*)As + lds_off(srow, s0))     = wa0;
        *(f16x8*)((char*)As + lds_off(srow, s0 + 1)) = wa1;
        *(f16x8*)((char*)Bs + lds_off(srow, s0))     = xa0;
        *(f16x8*)((char*)Bs + lds_off(srow, s0 + 1)) = xa1;
        __syncthreads();

        f16x8 af[4], bfr[4];
        #pragma unroll
        for (int i = 0; i < 4; ++i) {
            af[i]  = *(const f16x8*)((char*)As + lds_off(wr * 64 + i * 16 + fr, sl));
            bfr[i] = *(const f16x8*)((char*)Bs + lds_off(wc * 64 + i * 16 + fr, sl));
        }
        #pragma unroll
        for (int mi = 0; mi < 4; ++mi)
            #pragma unroll
            for (int ni = 0; ni < 4; ++ni)
                acc[mi][ni] = __builtin_amdgcn_mfma_f32_16x16x32_f16(
                    af[mi], bfr[ni], acc[mi][ni], 0, 0, 0);
    }

    // epilogue: D layout col = lane&15, row = (lane>>4)*4 + reg
    float* Pb = P + ((size_t)b * CT + bc) * N + bn;
    #pragma unroll
    for (int mi = 0; mi < 4; ++mi)
        #pragma unroll
        for (int ni = 0; ni < 4; ++ni)
            #pragma unroll
            for (int r = 0; r < 4; ++r) {
                const int row = wr * 64 + mi * 16 + sl * 4 + r;
                const int col = wc * 64 + ni * 16 + fr;
                Pb[(size_t)row * N + col] = acc[mi][ni][r];
            }
}

// ---------------------------------------------------------------------------
// K2: BN stats -> per-channel scale/shift (q and v channels only)
// ---------------------------------------------------------------------------
__global__ __launch_bounds__(256) void k_bnstats(
    const float* __restrict__ P,
    const float* __restrict__ gq, const float* __restrict__ bq,
    const float* __restrict__ gv, const float* __restrict__ bv,
    float* __restrict__ sArr, float* __restrict__ tArr)
{
    const int ci = blockIdx.x;              // 0..447
    const int c  = (ci < CQ) ? ci : ci + CK;
    float g, be;
    if (ci < CQ) { g = gq[ci];      be = bq[ci]; }
    else         { g = gv[ci - CQ]; be = bv[ci - CQ]; }

    const int tid = threadIdx.x;
    float s = 0.f, s2 = 0.f;
    for (int b = 0; b < B; ++b) {
        const float* row = P + ((size_t)b * CT + c) * N;
        #pragma unroll
        for (int i = 0; i < 4; ++i) {
            float4 v = *(const float4*)(row + (i * 256 + tid) * 4);
            s  += v.x + v.y + v.z + v.w;
            s2 += v.x*v.x + v.y*v.y + v.z*v.z + v.w*v.w;
        }
    }
    #pragma unroll
    for (int off = 32; off; off >>= 1) {
        s  += __shfl_xor(s, off);
        s2 += __shfl_xor(s2, off);
    }
    __shared__ float ls[4], ls2[4];
    if ((tid & 63) == 0) { ls[tid >> 6] = s; ls2[tid >> 6] = s2; }
    __syncthreads();
    if (tid == 0) {
        float S = ls[0] + ls[1] + ls[2] + ls[3];
        float S2 = ls2[0] + ls2[1] + ls2[2] + ls2[3];
        const float invM = 1.0f / (float)(B * N);
        float mean = S * invM;
        float var  = S2 * invM - mean * mean;
        float sc   = g / sqrtf(var + EPS);
        sArr[c] = sc;
        tArr[c] = be - mean * sc;
    }
}

// ---------------------------------------------------------------------------
// K3: apply BN affine in place (q and v channels)
// ---------------------------------------------------------------------------
__global__ __launch_bounds__(256) void k_bnapply(
    float* __restrict__ P, const float* __restrict__ sArr, const float* __restrict__ tArr)
{
    const int ci = blockIdx.x;
    const int c  = (ci < CQ) ? ci : ci + CK;
    const int b  = blockIdx.y;
    const float sc = sArr[c], tt = tArr[c];
    float* row = P + ((size_t)b * CT + c) * N;
    const int tid = threadIdx.x;
    #pragma unroll
    for (int i = 0; i < 4; ++i) {
        float4 v = *(float4*)(row + (i * 256 + tid) * 4);
        v.x = v.x * sc + tt; v.y = v.y * sc + tt;
        v.z = v.z * sc + tt; v.w = v.w * sc + tt;
        *(float4*)(row + (i * 256 + tid) * 4) = v;
    }
}

// ---------------------------------------------------------------------------
// K4: softmax over n for each k-channel row, in place
// ---------------------------------------------------------------------------
__global__ __launch_bounds__(256) void k_softmax(float* __restrict__ P)
{
    const int b = blockIdx.y, c = CQ + blockIdx.x;
    float* row = P + ((size_t)b * CT + c) * N;
    const int tid = threadIdx.x;
    float v[16];
    float m = -3.4e38f;
    #pragma unroll
    for (int i = 0; i < 4; ++i) {
        float4 t = *(const float4*)(row + (i * 256 + tid) * 4);
        v[i*4+0] = t.x; v[i*4+1] = t.y; v[i*4+2] = t.z; v[i*4+3] = t.w;
        m = fmaxf(m, fmaxf(fmaxf(t.x, t.y), fmaxf(t.z, t.w)));
    }
    #pragma unroll
    for (int off = 32; off; off >>= 1) m = fmaxf(m, __shfl_xor(m, off));
    __shared__ float rA[4], rB[4];
    if ((tid & 63) == 0) rA[tid >> 6] = m;
    __syncthreads();
    m = fmaxf(fmaxf(rA[0], rA[1]), fmaxf(rA[2], rA[3]));
    float s = 0.f;
    #pragma unroll
    for (int i = 0; i < 16; ++i) { v[i] = __expf(v[i] - m); s += v[i]; }
    #pragma unroll
    for (int off = 32; off; off >>= 1) s += __shfl_xor(s, off);
    if ((tid & 63) == 0) rB[tid >> 6] = s;
    __syncthreads();
    s = rB[0] + rB[1] + rB[2] + rB[3];
    const float inv = 1.f / s;
    #pragma unroll
    for (int i = 0; i < 4; ++i) {
        float4 t = {v[i*4+0]*inv, v[i*4+1]*inv, v[i*4+2]*inv, v[i*4+3]*inv};
        *(float4*)(row + (i * 256 + tid) * 4) = t;
    }
}

// ---------------------------------------------------------------------------
// K5: zero lam_c, then lam_c[b][k][v] += sum_{u,n} ksm[b][k*U+u][n]*vbn[b][v*U+u][n]
// ---------------------------------------------------------------------------
__global__ void k_zero(float* __restrict__ p)
{
    ((float4*)p)[blockIdx.x * 256 + threadIdx.x] = float4{0.f, 0.f, 0.f, 0.f};
}

__global__ __launch_bounds__(256) void k_lamc(
    const float* __restrict__ P, float* __restrict__ lamC)
{
    __shared__ float Kt[128][20];   // [n][k]
    __shared__ float Vt[128][68];   // [n][v]
    const int b = blockIdx.z, u = blockIdx.y;
    const int chunk0 = blockIdx.x * 512;
    const int tid = threadIdx.x;
    const int vv = tid & 63, kg = tid >> 6;
    float acc[4] = {0.f, 0.f, 0.f, 0.f};

    for (int sc = 0; sc < 4; ++sc) {
        const int nbase = chunk0 + sc * 128;
        __syncthreads();
        for (int idx = tid; idx < 16 * 128; idx += 256) {
            int kk = idx >> 7, n = idx & 127;
            Kt[n][kk] = P[((size_t)b * CT + CQ + kk * U + u) * N + nbase + n];
        }
        for (int idx = tid; idx < 64 * 128; idx += 256) {
            int vvv = idx >> 7, n = idx & 127;
            Vt[n][vvv] = P[((size_t)b * CT + CV0 + vvv * U + u) * N + nbase + n];
        }
        __syncthreads();
        #pragma unroll 4
        for (int n = 0; n < 128; ++n) {
            float4 kv = *(const float4*)&Kt[n][kg * 4];
            float vx = Vt[n][vv];
            acc[0] += kv.x * vx; acc[1] += kv.y * vx;
            acc[2] += kv.z * vx; acc[3] += kv.w * vx;
        }
    }
    #pragma unroll
    for (int j = 0; j < 4; ++j)
        atomicAdd(&lamC[((size_t)b * K + kg * 4 + j) * V + vv], acc[j]);
}

// ---------------------------------------------------------------------------
// K6: fused position-lambda conv + output
//   Y[b][n][h*64+v] = sum_k q[b][h*16+k][n] * ( lam_c[b][k][v] + lam_p[k][v][n] )
//   lam_p[k][v][n]  = sum_{u,l} vbn[b][v*4+u][n-11+l] * rel[k][u][l]
// ---------------------------------------------------------------------------
__global__ __launch_bounds__(256) void k_out(
    const float* __restrict__ P, const float* __restrict__ rel,
    const float* __restrict__ lamC, float* __restrict__ Y)
{
    __shared__ float vseg[4][38][64];     // [u][np][v]
    __shared__ float Wl[92][16];          // [(u*23+l)][k]
    __shared__ float qtile[12][16][16];   // [h][nn][k]

    const int b = blockIdx.y;
    const int n0 = blockIdx.x * 16;
    const int tid = threadIdx.x;

    {
        const int u = tid & 3, vv = tid >> 2;
        const float* row = P + ((size_t)b * CT + CV0 + tid) * N;
        for (int np = 0; np < 38; ++np) {
            const int n = n0 - PAD + np;
            vseg[u][np][vv] = (n >= 0 && n < N) ? row[n] : 0.f;
        }
    }
    if (tid < CQ) {
        const int h = tid >> 4, k = tid & 15;
        const float* row = P + ((size_t)b * CT + tid) * N + n0;
        for (int nn = 0; nn < 16; ++nn) qtile[h][nn][k] = row[nn];
    }
    for (int idx = tid; idx < K * U * L; idx += 256) {
        const int k = idx / (U * L), r = idx % (U * L);
        Wl[r][k] = rel[idx];
    }
    __syncthreads();

    const int vv4 = tid & 15;   // v = vv4*4 + vi
    const int nn  = tid >> 4;   // 0..15
    float lam[16][4];
    const float* lamCb = lamC + (size_t)b * K * V;
    #pragma unroll
    for (int k = 0; k < 16; ++k) {
        float4 lc = *(const float4*)(lamCb + k * V + vv4 * 4);
        lam[k][0] = lc.x; lam[k][1] = lc.y; lam[k][2] = lc.z; lam[k][3] = lc.w;
    }

    #pragma unroll 1
    for (int u = 0; u < 4; ++u) {
        #pragma unroll
        for (int l = 0; l < 23; ++l) {
            float4 vx = *(const float4*)&vseg[u][nn + l][vv4 * 4];
            const float vx4[4] = {vx.x, vx.y, vx.z, vx.w};
            #pragma unroll
            for (int kg = 0; kg < 4; ++kg) {
                float4 w = *(const float4*)&Wl[u * 23 + l][kg * 4];
                const float w4[4] = {w.x, w.y, w.z, w.w};
                #pragma unroll
                for (int j = 0; j < 4; ++j)
                    #pragma unroll
                    for (int vi = 0; vi < 4; ++vi)
                        lam[kg * 4 + j][vi] += w4[j] * vx4[vi];
            }
        }
    }

    const int n = n0 + nn;
    float* Yrow = Y + ((size_t)b * N + n) * (H * V);
    for (int h = 0; h < H; ++h) {
        float y[4] = {0.f, 0.f, 0.f, 0.f};
        #pragma unroll
        for (int kg = 0; kg < 4; ++kg) {
            float4 q4 = *(const float4*)&qtile[h][nn][kg * 4];
            const float qa[4] = {q4.x, q4.y, q4.z, q4.w};
            #pragma unroll
            for (int j = 0; j < 4; ++j)
                #pragma unroll
                for (int vi = 0; vi < 4; ++vi)
                    y[vi] += qa[j] * lam[kg * 4 + j][vi];
        }
        float4 o = {y[0], y[1], y[2], y[3]};
        *(float4*)(Yrow + h * 64 + vv4 * 4) = o;
    }
}

// ---------------------------------------------------------------------------
extern "C" void kernel_launch(void* const* d_in, const int* in_sizes, int n_in,
                              void* d_out, int out_size, void* d_ws, size_t ws_size,
                              hipStream_t stream)
{
    const float* x   = (const float*)d_in[0];
    const float* Wq  = (const float*)d_in[1];
    const float* Wk  = (const float*)d_in[2];
    const float* Wv  = (const float*)d_in[3];
    const float* gq  = (const float*)d_in[4];
    const float* bq  = (const float*)d_in[5];
    const float* gv  = (const float*)d_in[6];
    const float* bv  = (const float*)d_in[7];
    const float* rel = (const float*)d_in[8];
    float* Y = (float*)d_out;

    float* P    = (float*)d_ws;                       // B*CT*N floats (64 MiB)
    float* sArr = P + (size_t)B * CT * N;             // CT
    float* tArr = sArr + CT;                          // CT
    float* lamC = tArr + CT;                          // B*K*V = 8192

    k_proj   <<<dim3(N / 128, CT / 128, B), 256, 0, stream>>>(x, Wq, Wk, Wv, P);
    k_bnstats<<<dim3(CQ + CV), 256, 0, stream>>>(P, gq, bq, gv, bv, sArr, tArr);
    k_bnapply<<<dim3(CQ + CV, B), 256, 0, stream>>>(P, sArr, tArr);
    k_softmax<<<dim3(CK, B), 256, 0, stream>>>(P);
    k_zero   <<<dim3(8), 256, 0, stream>>>(lamC);
    k_lamc   <<<dim3(N / 512, U, B), 256, 0, stream>>>(P, lamC);
    k_out    <<<dim3(N / 16, B), 256, 0, stream>>>(P, rel, lamC, Y);
}

// Round 3
// 239.485 us; speedup vs baseline: 2.3230x; 1.2227x over previous
//
#include <hip/hip_runtime.h>
#include <hip/hip_bf16.h>

// Problem constants
constexpr int B = 8, N = 4096, D = 768;
constexpr int H = 12, K = 16, U = 4, V = 64, L = 23, PAD = 11;
constexpr int CQ = 192;           // q channels [0,192)
constexpr int CK = 64;            // k channels [192,256)
constexpr int CV = 256;           // v channels [256,512)
constexpr int CT = 512;           // total channels
constexpr int CV0 = CQ + CK;      // 256
constexpr float EPS = 1e-5f;

typedef _Float16 f16x8 __attribute__((ext_vector_type(8)));
typedef _Float16 f16x4 __attribute__((ext_vector_type(4)));
typedef float    f32x4 __attribute__((ext_vector_type(4)));

// ---------------------------------------------------------------------------
// K1: fused projection GEMM on MFMA (f16 inputs, fp32 accum) — unchanged
// ---------------------------------------------------------------------------
__device__ __forceinline__ int lds_off(int row, int slot) {
    int p = slot ^ (row & 3) ^ ((row >> 2) & 3);
    return row * 64 + p * 16;          // byte offset
}

__device__ __forceinline__ f16x8 cvt8(const float* __restrict__ p) {
    float4 a = *(const float4*)p;
    float4 b = *(const float4*)(p + 4);
    f16x8 r;
    r[0] = (_Float16)a.x; r[1] = (_Float16)a.y; r[2] = (_Float16)a.z; r[3] = (_Float16)a.w;
    r[4] = (_Float16)b.x; r[5] = (_Float16)b.y; r[6] = (_Float16)b.z; r[7] = (_Float16)b.w;
    return r;
}

__global__ __launch_bounds__(256) void k_proj(
    const float* __restrict__ x,
    const float* __restrict__ Wq, const float* __restrict__ Wk,
    const float* __restrict__ Wv, float* __restrict__ P)
{
    __shared__ _Float16 As[128 * 32];   // [row=c][col=d] swizzled
    __shared__ _Float16 Bs[128 * 32];   // [row=n][col=d] swizzled
    const int b  = blockIdx.z;
    const int bc = blockIdx.y * 128;
    const int bn = blockIdx.x * 128;
    const int tid  = threadIdx.x;
    const int lane = tid & 63;
    const int wave = tid >> 6;
    const int wr = wave >> 1, wc = wave & 1;

    const int srow  = tid >> 1;
    const int scolg = (tid & 1) * 16;
    const int s0    = (tid & 1) * 2;
    const int c = bc + srow;
    const float* wrow;
    if (c < CQ)       wrow = Wq + (size_t)c * D;
    else if (c < CV0) wrow = Wk + (size_t)(c - CQ) * D;
    else              wrow = Wv + (size_t)(c - CV0) * D;
    const float* xrow = x + ((size_t)b * N + bn + srow) * D;

    const int fr = lane & 15;
    const int sl = lane >> 4;

    f32x4 acc[4][4] = {};

    for (int kt = 0; kt < D; kt += 32) {
        f16x8 wa0 = cvt8(wrow + kt + scolg);
        f16x8 wa1 = cvt8(wrow + kt + scolg + 8);
        f16x8 xa0 = cvt8(xrow + kt + scolg);
        f16x8 xa1 = cvt8(xrow + kt + scolg + 8);
        __syncthreads();
        *(f16x8*)((char*)As + lds_off(srow, s0))     = wa0;
        *(f16x8*)((char*)As + lds_off(srow, s0 + 1)) = wa1;
        *(f16x8*)((char*)Bs + lds_off(srow, s0))     = xa0;
        *(f16x8*)((char*)Bs + lds_off(srow, s0 + 1)) = xa1;
        __syncthreads();

        f16x8 af[4], bfr[4];
        #pragma unroll
        for (int i = 0; i < 4; ++i) {
            af[i]  = *(const f16x8*)((char*)As + lds_off(wr * 64 + i * 16 + fr, sl));
            bfr[i] = *(const f16x8*)((char*)Bs + lds_off(wc * 64 + i * 16 + fr, sl));
        }
        #pragma unroll
        for (int mi = 0; mi < 4; ++mi)
            #pragma unroll
            for (int ni = 0; ni < 4; ++ni)
                acc[mi][ni] = __builtin_amdgcn_mfma_f32_16x16x32_f16(
                    af[mi], bfr[ni], acc[mi][ni], 0, 0, 0);
    }

    float* Pb = P + ((size_t)b * CT + bc) * N + bn;
    #pragma unroll
    for (int mi = 0; mi < 4; ++mi)
        #pragma unroll
        for (int ni = 0; ni < 4; ++ni)
            #pragma unroll
            for (int r = 0; r < 4; ++r) {
                const int row = wr * 64 + mi * 16 + sl * 4 + r;
                const int col = wc * 64 + ni * 16 + fr;
                Pb[(size_t)row * N + col] = acc[mi][ni][r];
            }
}

// ---------------------------------------------------------------------------
// K2: BN stats -> per-channel scale/shift (q and v channels only), on raw P
// ---------------------------------------------------------------------------
__global__ __launch_bounds__(256) void k_bnstats(
    const float* __restrict__ P,
    const float* __restrict__ gq, const float* __restrict__ bq,
    const float* __restrict__ gv, const float* __restrict__ bv,
    float* __restrict__ sArr, float* __restrict__ tArr)
{
    const int ci = blockIdx.x;              // 0..447
    const int c  = (ci < CQ) ? ci : ci + CK;
    float g, be;
    if (ci < CQ) { g = gq[ci];      be = bq[ci]; }
    else         { g = gv[ci - CQ]; be = bv[ci - CQ]; }

    const int tid = threadIdx.x;
    float s = 0.f, s2 = 0.f;
    for (int b = 0; b < B; ++b) {
        const float* row = P + ((size_t)b * CT + c) * N;
        #pragma unroll
        for (int i = 0; i < 4; ++i) {
            float4 v = *(const float4*)(row + (i * 256 + tid) * 4);
            s  += v.x + v.y + v.z + v.w;
            s2 += v.x*v.x + v.y*v.y + v.z*v.z + v.w*v.w;
        }
    }
    #pragma unroll
    for (int off = 32; off; off >>= 1) {
        s  += __shfl_xor(s, off);
        s2 += __shfl_xor(s2, off);
    }
    __shared__ float ls[4], ls2[4];
    if ((tid & 63) == 0) { ls[tid >> 6] = s; ls2[tid >> 6] = s2; }
    __syncthreads();
    if (tid == 0) {
        float S = ls[0] + ls[1] + ls[2] + ls[3];
        float S2 = ls2[0] + ls2[1] + ls2[2] + ls2[3];
        const float invM = 1.0f / (float)(B * N);
        float mean = S * invM;
        float var  = S2 * invM - mean * mean;
        float sc   = g / sqrtf(var + EPS);
        sArr[c] = sc;
        tArr[c] = be - mean * sc;
    }
}

// ---------------------------------------------------------------------------
// K3: softmax row stats for k channels: max and 1/sum(exp(x-max)) per (b,kc)
// ---------------------------------------------------------------------------
__global__ __launch_bounds__(256) void k_kstats(
    const float* __restrict__ P, float* __restrict__ mxk, float* __restrict__ invk)
{
    const int b = blockIdx.y, kc = blockIdx.x;
    const float* row = P + ((size_t)b * CT + CQ + kc) * N;
    const int tid = threadIdx.x;
    float v[16];
    float m = -3.4e38f;
    #pragma unroll
    for (int i = 0; i < 4; ++i) {
        float4 t = *(const float4*)(row + (i * 256 + tid) * 4);
        v[i*4+0] = t.x; v[i*4+1] = t.y; v[i*4+2] = t.z; v[i*4+3] = t.w;
        m = fmaxf(m, fmaxf(fmaxf(t.x, t.y), fmaxf(t.z, t.w)));
    }
    #pragma unroll
    for (int off = 32; off; off >>= 1) m = fmaxf(m, __shfl_xor(m, off));
    __shared__ float rA[4], rB[4];
    if ((tid & 63) == 0) rA[tid >> 6] = m;
    __syncthreads();
    m = fmaxf(fmaxf(rA[0], rA[1]), fmaxf(rA[2], rA[3]));
    float s = 0.f;
    #pragma unroll
    for (int i = 0; i < 16; ++i) s += __expf(v[i] - m);
    #pragma unroll
    for (int off = 32; off; off >>= 1) s += __shfl_xor(s, off);
    if ((tid & 63) == 0) rB[tid >> 6] = s;
    __syncthreads();
    if (tid == 0) {
        s = rB[0] + rB[1] + rB[2] + rB[3];
        mxk[b * CK + kc]  = m;
        invk[b * CK + kc] = 1.f / s;
    }
}

// ---------------------------------------------------------------------------
// K4: zero lam_c
// ---------------------------------------------------------------------------
__global__ void k_zero(float* __restrict__ p)
{
    ((float4*)p)[blockIdx.x * 256 + threadIdx.x] = float4{0.f, 0.f, 0.f, 0.f};
}

// ---------------------------------------------------------------------------
// K5: lam_c[b][k][v] += sum_{u,n} softmax(k)[b][k*U+u][n] * bn(v)[b][v*U+u][n]
//     softmax + BN applied on the fly from raw P
// ---------------------------------------------------------------------------
__global__ __launch_bounds__(256) void k_lamc(
    const float* __restrict__ P, const float* __restrict__ mxk,
    const float* __restrict__ invk, const float* __restrict__ sArr,
    const float* __restrict__ tArr, float* __restrict__ lamC)
{
    __shared__ float Kt[128][20];   // [n][k]
    __shared__ float Vt[128][68];   // [n][v]
    const int b = blockIdx.z, u = blockIdx.y;
    const int chunk0 = blockIdx.x * 512;
    const int tid = threadIdx.x;
    const int vv = tid & 63, kg = tid >> 6;
    float acc[4] = {0.f, 0.f, 0.f, 0.f};

    for (int sc = 0; sc < 4; ++sc) {
        const int nbase = chunk0 + sc * 128;
        __syncthreads();
        for (int idx = tid; idx < 16 * 128; idx += 256) {
            int kk = idx >> 7, n = idx & 127;
            int kc = kk * U + u;
            float raw = P[((size_t)b * CT + CQ + kc) * N + nbase + n];
            Kt[n][kk] = __expf(raw - mxk[b * CK + kc]) * invk[b * CK + kc];
        }
        for (int idx = tid; idx < 64 * 128; idx += 256) {
            int vvv = idx >> 7, n = idx & 127;
            int c = CV0 + vvv * U + u;
            float raw = P[((size_t)b * CT + c) * N + nbase + n];
            Vt[n][vvv] = raw * sArr[c] + tArr[c];
        }
        __syncthreads();
        #pragma unroll 4
        for (int n = 0; n < 128; ++n) {
            float4 kv = *(const float4*)&Kt[n][kg * 4];
            float vx = Vt[n][vv];
            acc[0] += kv.x * vx; acc[1] += kv.y * vx;
            acc[2] += kv.z * vx; acc[3] += kv.w * vx;
        }
    }
    #pragma unroll
    for (int j = 0; j < 4; ++j)
        atomicAdd(&lamC[((size_t)b * K + kg * 4 + j) * V + vv], acc[j]);
}

// ---------------------------------------------------------------------------
// K6: fused position-lambda conv + output (rewritten)
//   block = (b, 32-position tile), 512 threads = 8 waves
//   thread = (vv4 = tid&15: group of 4 v) x (nn = tid>>4: position 0..31)
//   BN applied on the fly during staging; coalesced staging (lanes along n).
//   LDS: vseg fp32 [4][54][66] (2-way-free b64 reads, conflict-free writes),
//        qtile f16 [32][208] (broadcast reads), Wl fp32 [92][16] (broadcast).
// ---------------------------------------------------------------------------
__global__ __launch_bounds__(512, 4) void k_out(
    const float* __restrict__ P, const float* __restrict__ rel,
    const float* __restrict__ lamC, const float* __restrict__ sArr,
    const float* __restrict__ tArr, float* __restrict__ Y)
{
    constexpr int NT = 32;
    constexpr int NP = NT + L - 1;        // 54
    __shared__ float    vseg[4][NP][66];  // [u][np][v]
    __shared__ _Float16 qtile[NT][208];   // [pos][ch]
    __shared__ float    Wl[92][16];       // [(u*23+l)][k]

    const int b  = blockIdx.y;
    const int n0 = blockIdx.x * NT;
    const int tid  = threadIdx.x;
    const int lane = tid & 63;
    const int wave = tid >> 6;

    // --- stage v halo (BN fused): wave w -> channels 32w..32w+31, lane = np
    {
        for (int i = 0; i < 32; ++i) {
            const int ch = wave * 32 + i;          // 0..255
            const int c  = CV0 + ch;
            const int n  = n0 - PAD + lane;
            float val = 0.f;
            if (lane < NP && n >= 0 && n < N)
                val = P[((size_t)b * CT + c) * N + n] * sArr[c] + tArr[c];
            if (lane < NP)
                vseg[ch & 3][lane][ch >> 2] = val;
        }
    }
    // --- stage q tile (BN fused): idx = ch*32 + pos, coalesced over pos
    for (int idx = tid; idx < CQ * NT; idx += 512) {
        const int ch = idx >> 5, pos = idx & 31;
        float val = P[((size_t)b * CT + ch) * N + n0 + pos] * sArr[ch] + tArr[ch];
        qtile[pos][ch] = (_Float16)val;
    }
    // --- stage rel weights transposed: Wl[u*23+l][k]
    for (int idx = tid; idx < K * U * L; idx += 512) {
        const int k = idx / (U * L), r = idx % (U * L);
        Wl[r][k] = rel[idx];
    }
    __syncthreads();

    const int vv4 = tid & 15;   // v = vv4*4 + vi
    const int nn  = tid >> 4;   // 0..31

    float lam[16][4];
    const float* lamCb = lamC + (size_t)b * K * V;
    #pragma unroll
    for (int k = 0; k < 16; ++k) {
        float4 lc = *(const float4*)(lamCb + k * V + vv4 * 4);
        lam[k][0] = lc.x; lam[k][1] = lc.y; lam[k][2] = lc.z; lam[k][3] = lc.w;
    }

    #pragma unroll 1
    for (int u = 0; u < 4; ++u) {
        #pragma unroll
        for (int l = 0; l < 23; ++l) {
            const float* vp = &vseg[u][nn + l][vv4 * 4];
            float2 va = *(const float2*)vp;
            float2 vb = *(const float2*)(vp + 2);
            const float vx4[4] = {va.x, va.y, vb.x, vb.y};
            #pragma unroll
            for (int kg = 0; kg < 4; ++kg) {
                float4 w = *(const float4*)&Wl[u * 23 + l][kg * 4];
                const float w4[4] = {w.x, w.y, w.z, w.w};
                #pragma unroll
                for (int j = 0; j < 4; ++j)
                    #pragma unroll
                    for (int vi = 0; vi < 4; ++vi)
                        lam[kg * 4 + j][vi] += w4[j] * vx4[vi];
            }
        }
    }

    const int n = n0 + nn;
    float* Yrow = Y + ((size_t)b * N + n) * (H * V);
    #pragma unroll 1
    for (int h = 0; h < H; ++h) {
        float y[4] = {0.f, 0.f, 0.f, 0.f};
        #pragma unroll
        for (int kg = 0; kg < 4; ++kg) {
            f16x4 q4 = *(const f16x4*)&qtile[nn][h * 16 + kg * 4];
            const float qa[4] = {(float)q4[0], (float)q4[1], (float)q4[2], (float)q4[3]};
            #pragma unroll
            for (int j = 0; j < 4; ++j)
                #pragma unroll
                for (int vi = 0; vi < 4; ++vi)
                    y[vi] += qa[j] * lam[kg * 4 + j][vi];
        }
        float4 o = {y[0], y[1], y[2], y[3]};
        *(float4*)(Yrow + h * 64 + vv4 * 4) = o;
    }
}

// ---------------------------------------------------------------------------
extern "C" void kernel_launch(void* const* d_in, const int* in_sizes, int n_in,
                              void* d_out, int out_size, void* d_ws, size_t ws_size,
                              hipStream_t stream)
{
    const float* x   = (const float*)d_in[0];
    const float* Wq  = (const float*)d_in[1];
    const float* Wk  = (const float*)d_in[2];
    const float* Wv  = (const float*)d_in[3];
    const float* gq  = (const float*)d_in[4];
    const float* bq  = (const float*)d_in[5];
    const float* gv  = (const float*)d_in[6];
    const float* bv  = (const float*)d_in[7];
    const float* rel = (const float*)d_in[8];
    float* Y = (float*)d_out;

    float* P    = (float*)d_ws;                       // B*CT*N floats (64 MiB)
    float* sArr = P + (size_t)B * CT * N;             // CT
    float* tArr = sArr + CT;                          // CT
    float* lamC = tArr + CT;                          // B*K*V = 8192
    float* mxk  = lamC + (size_t)B * K * V;           // B*CK = 512
    float* invk = mxk + B * CK;                       // B*CK = 512

    k_proj   <<<dim3(N / 128, CT / 128, B), 256, 0, stream>>>(x, Wq, Wk, Wv, P);
    k_bnstats<<<dim3(CQ + CV), 256, 0, stream>>>(P, gq, bq, gv, bv, sArr, tArr);
    k_kstats <<<dim3(CK, B), 256, 0, stream>>>(P, mxk, invk);
    k_zero   <<<dim3(8), 256, 0, stream>>>(lamC);
    k_lamc   <<<dim3(N / 512, U, B), 256, 0, stream>>>(P, mxk, invk, sArr, tArr, lamC);
    k_out    <<<dim3(N / 32, B), 512, 0, stream>>>(P, rel, lamC, sArr, tArr, Y);
}

// Round 4
// 195.139 us; speedup vs baseline: 2.8509x; 1.2273x over previous
//
#include <hip/hip_runtime.h>
#include <hip/hip_bf16.h>

// Problem constants
constexpr int B = 8, N = 4096, D = 768;
constexpr int H = 12, K = 16, U = 4, V = 64, L = 23, PAD = 11;
constexpr int CQ = 192;           // q channels [0,192)
constexpr int CK = 64;            // k channels [192,256)
constexpr int CV = 256;           // v channels [256,512)
constexpr int CT = 512;           // total channels
constexpr int CV0 = CQ + CK;      // 256
constexpr float EPS = 1e-5f;

typedef _Float16 f16x8 __attribute__((ext_vector_type(8)));
typedef _Float16 f16x4 __attribute__((ext_vector_type(4)));
typedef float    f32x4 __attribute__((ext_vector_type(4)));

// ---------------------------------------------------------------------------
// K1: fused projection GEMM on MFMA (f16 inputs, fp32 accum)
//   XCD-chunked swizzle: the 4 bc-blocks sharing one x-tile land on the same
//   XCD (dispatch ids differ by 8 -> same id mod 8 -> same XCD) for L2 reuse.
// ---------------------------------------------------------------------------
__device__ __forceinline__ int lds_off(int row, int slot) {
    int p = slot ^ (row & 3) ^ ((row >> 2) & 3);
    return row * 64 + p * 16;          // byte offset
}

__device__ __forceinline__ f16x8 cvt8(const float* __restrict__ p) {
    float4 a = *(const float4*)p;
    float4 b = *(const float4*)(p + 4);
    f16x8 r;
    r[0] = (_Float16)a.x; r[1] = (_Float16)a.y; r[2] = (_Float16)a.z; r[3] = (_Float16)a.w;
    r[4] = (_Float16)b.x; r[5] = (_Float16)b.y; r[6] = (_Float16)b.z; r[7] = (_Float16)b.w;
    return r;
}

__global__ __launch_bounds__(256) void k_proj(
    const float* __restrict__ x,
    const float* __restrict__ Wq, const float* __restrict__ Wk,
    const float* __restrict__ Wv, float* __restrict__ P)
{
    __shared__ _Float16 As[128 * 32];   // [row=c][col=d] swizzled
    __shared__ _Float16 Bs[128 * 32];   // [row=n][col=d] swizzled

    // swizzled decode: group g=(b,bn) owns 4 bc-blocks at ids X+8*(4*(g>>3)+bc)
    const int Ld = blockIdx.x;
    const int X  = Ld & 7, j = Ld >> 3;
    const int bcT = j & 3;
    const int g   = (j >> 2) * 8 + X;    // 0..255
    const int bnT = g & 31;
    const int b   = g >> 5;
    const int bc  = bcT * 128;
    const int bn  = bnT * 128;

    const int tid  = threadIdx.x;
    const int lane = tid & 63;
    const int wave = tid >> 6;
    const int wr = wave >> 1, wc = wave & 1;

    const int srow  = tid >> 1;
    const int scolg = (tid & 1) * 16;
    const int s0    = (tid & 1) * 2;
    const int c = bc + srow;
    const float* wrow;
    if (c < CQ)       wrow = Wq + (size_t)c * D;
    else if (c < CV0) wrow = Wk + (size_t)(c - CQ) * D;
    else              wrow = Wv + (size_t)(c - CV0) * D;
    const float* xrow = x + ((size_t)b * N + bn + srow) * D;

    const int fr = lane & 15;
    const int sl = lane >> 4;

    f32x4 acc[4][4] = {};

    for (int kt = 0; kt < D; kt += 32) {
        f16x8 wa0 = cvt8(wrow + kt + scolg);
        f16x8 wa1 = cvt8(wrow + kt + scolg + 8);
        f16x8 xa0 = cvt8(xrow + kt + scolg);
        f16x8 xa1 = cvt8(xrow + kt + scolg + 8);
        __syncthreads();
        *(f16x8*)((char*)As + lds_off(srow, s0))     = wa0;
        *(f16x8*)((char*)As + lds_off(srow, s0 + 1)) = wa1;
        *(f16x8*)((char*)Bs + lds_off(srow, s0))     = xa0;
        *(f16x8*)((char*)Bs + lds_off(srow, s0 + 1)) = xa1;
        __syncthreads();

        f16x8 af[4], bfr[4];
        #pragma unroll
        for (int i = 0; i < 4; ++i) {
            af[i]  = *(const f16x8*)((char*)As + lds_off(wr * 64 + i * 16 + fr, sl));
            bfr[i] = *(const f16x8*)((char*)Bs + lds_off(wc * 64 + i * 16 + fr, sl));
        }
        #pragma unroll
        for (int mi = 0; mi < 4; ++mi)
            #pragma unroll
            for (int ni = 0; ni < 4; ++ni)
                acc[mi][ni] = __builtin_amdgcn_mfma_f32_16x16x32_f16(
                    af[mi], bfr[ni], acc[mi][ni], 0, 0, 0);
    }

    float* Pb = P + ((size_t)b * CT + bc) * N + bn;
    #pragma unroll
    for (int mi = 0; mi < 4; ++mi)
        #pragma unroll
        for (int ni = 0; ni < 4; ++ni)
            #pragma unroll
            for (int r = 0; r < 4; ++r) {
                const int row = wr * 64 + mi * 16 + sl * 4 + r;
                const int col = wc * 64 + ni * 16 + fr;
                Pb[(size_t)row * N + col] = acc[mi][ni][r];
            }
}

// ---------------------------------------------------------------------------
// K2: BN stats -> per-channel scale/shift (q and v channels only), on raw P
// ---------------------------------------------------------------------------
__global__ __launch_bounds__(256) void k_bnstats(
    const float* __restrict__ P,
    const float* __restrict__ gq, const float* __restrict__ bq,
    const float* __restrict__ gv, const float* __restrict__ bv,
    float* __restrict__ sArr, float* __restrict__ tArr)
{
    const int ci = blockIdx.x;              // 0..447
    const int c  = (ci < CQ) ? ci : ci + CK;
    float g, be;
    if (ci < CQ) { g = gq[ci];      be = bq[ci]; }
    else         { g = gv[ci - CQ]; be = bv[ci - CQ]; }

    const int tid = threadIdx.x;
    float s = 0.f, s2 = 0.f;
    for (int b = 0; b < B; ++b) {
        const float* row = P + ((size_t)b * CT + c) * N;
        #pragma unroll
        for (int i = 0; i < 4; ++i) {
            float4 v = *(const float4*)(row + (i * 256 + tid) * 4);
            s  += v.x + v.y + v.z + v.w;
            s2 += v.x*v.x + v.y*v.y + v.z*v.z + v.w*v.w;
        }
    }
    #pragma unroll
    for (int off = 32; off; off >>= 1) {
        s  += __shfl_xor(s, off);
        s2 += __shfl_xor(s2, off);
    }
    __shared__ float ls[4], ls2[4];
    if ((tid & 63) == 0) { ls[tid >> 6] = s; ls2[tid >> 6] = s2; }
    __syncthreads();
    if (tid == 0) {
        float S = ls[0] + ls[1] + ls[2] + ls[3];
        float S2 = ls2[0] + ls2[1] + ls2[2] + ls2[3];
        const float invM = 1.0f / (float)(B * N);
        float mean = S * invM;
        float var  = S2 * invM - mean * mean;
        float sc   = g / sqrtf(var + EPS);
        sArr[c] = sc;
        tArr[c] = be - mean * sc;
    }
}

// ---------------------------------------------------------------------------
// K3: softmax row stats for k channels: max and 1/sum(exp(x-max)) per (b,kc)
// ---------------------------------------------------------------------------
__global__ __launch_bounds__(256) void k_kstats(
    const float* __restrict__ P, float* __restrict__ mxk, float* __restrict__ invk)
{
    const int b = blockIdx.y, kc = blockIdx.x;
    const float* row = P + ((size_t)b * CT + CQ + kc) * N;
    const int tid = threadIdx.x;
    float v[16];
    float m = -3.4e38f;
    #pragma unroll
    for (int i = 0; i < 4; ++i) {
        float4 t = *(const float4*)(row + (i * 256 + tid) * 4);
        v[i*4+0] = t.x; v[i*4+1] = t.y; v[i*4+2] = t.z; v[i*4+3] = t.w;
        m = fmaxf(m, fmaxf(fmaxf(t.x, t.y), fmaxf(t.z, t.w)));
    }
    #pragma unroll
    for (int off = 32; off; off >>= 1) m = fmaxf(m, __shfl_xor(m, off));
    __shared__ float rA[4], rB[4];
    if ((tid & 63) == 0) rA[tid >> 6] = m;
    __syncthreads();
    m = fmaxf(fmaxf(rA[0], rA[1]), fmaxf(rA[2], rA[3]));
    float s = 0.f;
    #pragma unroll
    for (int i = 0; i < 16; ++i) s += __expf(v[i] - m);
    #pragma unroll
    for (int off = 32; off; off >>= 1) s += __shfl_xor(s, off);
    if ((tid & 63) == 0) rB[tid >> 6] = s;
    __syncthreads();
    if (tid == 0) {
        s = rB[0] + rB[1] + rB[2] + rB[3];
        mxk[b * CK + kc]  = m;
        invk[b * CK + kc] = 1.f / s;
    }
}

// ---------------------------------------------------------------------------
// K3b: qT[b][n][ch] = f16( BN(P[b][ch][n]) ), ch < 192  (tiled transpose)
// ---------------------------------------------------------------------------
__global__ __launch_bounds__(256) void k_qt(
    const float* __restrict__ P, const float* __restrict__ sArr,
    const float* __restrict__ tArr, _Float16* __restrict__ qT)
{
    __shared__ _Float16 tl[64][34];
    const int b  = blockIdx.z;
    const int c0 = blockIdx.y * 32;
    const int n0 = blockIdx.x * 64;
    const int tid = threadIdx.x;
    #pragma unroll
    for (int rep = 0; rep < 2; ++rep) {
        int idx = rep * 256 + tid;          // 0..511
        int ch = idx >> 4, f4 = idx & 15;
        int c = c0 + ch;
        float4 v = *(const float4*)(P + ((size_t)b * CT + c) * N + n0 + f4 * 4);
        float sc = sArr[c], tt = tArr[c];
        tl[f4*4+0][ch] = (_Float16)(v.x*sc+tt);
        tl[f4*4+1][ch] = (_Float16)(v.y*sc+tt);
        tl[f4*4+2][ch] = (_Float16)(v.z*sc+tt);
        tl[f4*4+3][ch] = (_Float16)(v.w*sc+tt);
    }
    __syncthreads();
    const int n = tid >> 2, part = tid & 3;
    f16x8 o;
    #pragma unroll
    for (int i = 0; i < 8; ++i) o[i] = tl[n][part*8+i];
    *(f16x8*)(qT + ((size_t)b * N + n0 + n) * CQ + c0 + part*8) = o;
}

// ---------------------------------------------------------------------------
// K4: zero lam_c
// ---------------------------------------------------------------------------
__global__ void k_zero(float* __restrict__ p)
{
    ((float4*)p)[blockIdx.x * 256 + threadIdx.x] = float4{0.f, 0.f, 0.f, 0.f};
}

// ---------------------------------------------------------------------------
// K5: lam_c[b][k][v] += sum_{u,n} softmax(k)[b][k*U+u][n] * bn(v)[b][v*U+u][n]
// ---------------------------------------------------------------------------
__global__ __launch_bounds__(256) void k_lamc(
    const float* __restrict__ P, const float* __restrict__ mxk,
    const float* __restrict__ invk, const float* __restrict__ sArr,
    const float* __restrict__ tArr, float* __restrict__ lamC)
{
    __shared__ float Kt[128][20];   // [n][k]
    __shared__ float Vt[128][68];   // [n][v]
    const int b = blockIdx.z, u = blockIdx.y;
    const int chunk0 = blockIdx.x * 512;
    const int tid = threadIdx.x;
    const int vv = tid & 63, kg = tid >> 6;
    float acc[4] = {0.f, 0.f, 0.f, 0.f};

    for (int sc = 0; sc < 4; ++sc) {
        const int nbase = chunk0 + sc * 128;
        __syncthreads();
        for (int idx = tid; idx < 16 * 128; idx += 256) {
            int kk = idx >> 7, n = idx & 127;
            int kc = kk * U + u;
            float raw = P[((size_t)b * CT + CQ + kc) * N + nbase + n];
            Kt[n][kk] = __expf(raw - mxk[b * CK + kc]) * invk[b * CK + kc];
        }
        for (int idx = tid; idx < 64 * 128; idx += 256) {
            int vvv = idx >> 7, n = idx & 127;
            int c = CV0 + vvv * U + u;
            float raw = P[((size_t)b * CT + c) * N + nbase + n];
            Vt[n][vvv] = raw * sArr[c] + tArr[c];
        }
        __syncthreads();
        #pragma unroll 4
        for (int n = 0; n < 128; ++n) {
            float4 kv = *(const float4*)&Kt[n][kg * 4];
            float vx = Vt[n][vv];
            acc[0] += kv.x * vx; acc[1] += kv.y * vx;
            acc[2] += kv.z * vx; acc[3] += kv.w * vx;
        }
    }
    #pragma unroll
    for (int j = 0; j < 4; ++j)
        atomicAdd(&lamC[((size_t)b * K + kg * 4 + j) * V + vv], acc[j]);
}

// ---------------------------------------------------------------------------
// K6: fused conv + output, MFMA formulation.
//   Per (nn, vg) tile: lam[16k x 16v] = lamC + sum_u relS(d,u)[16x32j] x
//       vsegT(u)[32j x 16v], window j at A = nn&~7, shift d = nn&7 folded
//       into 8 pre-shifted rel copies. Then Y-tile = qA(16h x 16k) x lam16.
//   512 thr / 8 waves: wave = (vg = w&3, nn-half = w>>2).
// ---------------------------------------------------------------------------
__global__ __launch_bounds__(512, 4) void k_out(
    const float* __restrict__ P, const float* __restrict__ rel,
    const float* __restrict__ lamC, const float* __restrict__ sArr,
    const float* __restrict__ tArr, const _Float16* __restrict__ qT,
    float* __restrict__ Y)
{
    constexpr int NT = 32;
    constexpr int VST = 72;                  // np stride (f16), mult of 8
    __shared__ _Float16 vsegT[256 * VST];    // [u*64+v][np]  (np 0..55 used)
    __shared__ _Float16 relS[8 * 4 * 16 * 32]; // [d][u][k][j]

    const int b  = blockIdx.y;
    const int n0 = blockIdx.x * NT;
    const int tid  = threadIdx.x;
    const int lane = tid & 63;
    const int wave = tid >> 6;
    const int fr = lane & 15;   // k row / v col / h row
    const int sl = lane >> 4;   // slot 0..3

    // --- stage vsegT: wave w -> channels w*32..w*32+31, lane = np
    for (int i = 0; i < 32; ++i) {
        const int ch  = wave * 32 + i;            // = v*4+u
        const int c   = CV0 + ch;
        const int row = (ch & 3) * 64 + (ch >> 2);
        const int n   = n0 - PAD + lane;
        float val = 0.f;
        if (lane < 54 && n >= 0 && n < N)
            val = P[((size_t)b * CT + c) * N + n] * sArr[c] + tArr[c];
        if (lane < 56)
            vsegT[row * VST + lane] = (_Float16)val;
    }
    // --- stage shifted rel: relS[d][u][k][j] = rel[k][u][j-d] (0 outside)
    for (int idx = tid; idx < 8 * 4 * 16 * 32; idx += 512) {
        const int jj = idx & 31, kk = (idx >> 5) & 15;
        const int uu = (idx >> 9) & 3, dd = idx >> 11;
        const int l = jj - dd;
        float vv = (l >= 0 && l < L) ? rel[(kk * U + uu) * L + l] : 0.f;
        relS[idx] = (_Float16)vv;
    }
    // --- lamC fragment (C-layout): row k = sl*4+r, col v = vg*16+fr
    const int vg = wave & 3;
    const int nb = (wave >> 2) * 16;
    float lc[4];
    #pragma unroll
    for (int r = 0; r < 4; ++r)
        lc[r] = lamC[(size_t)b * K * V + (sl * 4 + r) * V + vg * 16 + fr];
    __syncthreads();

    const _Float16* qTb = qT + (size_t)b * N * CQ;

    for (int dlt = 0; dlt < 8; ++dlt) {
        f16x8 aU[4];
        #pragma unroll
        for (int u = 0; u < 4; ++u)
            aU[u] = *(const f16x8*)(relS + ((dlt * 4 + u) * 16 + fr) * 32 + sl * 8);
        #pragma unroll
        for (int rep = 0; rep < 2; ++rep) {
            const int A  = nb + rep * 8;
            const int nn = A + dlt;
            f32x4 acc = {lc[0], lc[1], lc[2], lc[3]};
            #pragma unroll
            for (int u = 0; u < 4; ++u) {
                f16x8 bf = *(const f16x8*)(vsegT + (u * 64 + vg * 16 + fr) * VST + A + sl * 8);
                acc = __builtin_amdgcn_mfma_f32_16x16x32_f16(aU[u], bf, acc, 0, 0, 0);
            }
            f16x4 lam16;
            #pragma unroll
            for (int r = 0; r < 4; ++r) lam16[r] = (_Float16)acc[r];
            f16x4 q4 = *(const f16x4*)(qTb + (size_t)(n0 + nn) * CQ + fr * 16 + sl * 4);
            f32x4 y = {0.f, 0.f, 0.f, 0.f};
            y = __builtin_amdgcn_mfma_f32_16x16x16f16(q4, lam16, y, 0, 0, 0);
            if (sl < 3) {
                float* yr = Y + ((size_t)b * N + n0 + nn) * (H * V) + vg * 16 + fr;
                #pragma unroll
                for (int r = 0; r < 4; ++r)
                    yr[(sl * 4 + r) * 64] = y[r];
            }
        }
    }
}

// ---------------------------------------------------------------------------
extern "C" void kernel_launch(void* const* d_in, const int* in_sizes, int n_in,
                              void* d_out, int out_size, void* d_ws, size_t ws_size,
                              hipStream_t stream)
{
    const float* x   = (const float*)d_in[0];
    const float* Wq  = (const float*)d_in[1];
    const float* Wk  = (const float*)d_in[2];
    const float* Wv  = (const float*)d_in[3];
    const float* gq  = (const float*)d_in[4];
    const float* bq  = (const float*)d_in[5];
    const float* gv  = (const float*)d_in[6];
    const float* bv  = (const float*)d_in[7];
    const float* rel = (const float*)d_in[8];
    float* Y = (float*)d_out;

    float* P    = (float*)d_ws;                       // B*CT*N floats (64 MiB)
    float* sArr = P + (size_t)B * CT * N;             // CT
    float* tArr = sArr + CT;                          // CT
    float* lamC = tArr + CT;                          // B*K*V = 8192
    float* mxk  = lamC + (size_t)B * K * V;           // B*CK
    float* invk = mxk + B * CK;                       // B*CK
    _Float16* qT = (_Float16*)(invk + B * CK);        // B*N*CQ f16 (12.6 MB)

    k_proj   <<<dim3((N / 128) * (CT / 128) * B), 256, 0, stream>>>(x, Wq, Wk, Wv, P);
    k_bnstats<<<dim3(CQ + CV), 256, 0, stream>>>(P, gq, bq, gv, bv, sArr, tArr);
    k_kstats <<<dim3(CK, B), 256, 0, stream>>>(P, mxk, invk);
    k_qt     <<<dim3(N / 64, CQ / 32, B), 256, 0, stream>>>(P, sArr, tArr, qT);
    k_zero   <<<dim3(8), 256, 0, stream>>>(lamC);
    k_lamc   <<<dim3(N / 512, U, B), 256, 0, stream>>>(P, mxk, invk, sArr, tArr, lamC);
    k_out    <<<dim3(N / 32, B), 512, 0, stream>>>(P, rel, lamC, sArr, tArr, qT, Y);
}

// Round 5
// 157.099 us; speedup vs baseline: 3.5412x; 1.2421x over previous
//
#include <hip/hip_runtime.h>
#include <hip/hip_bf16.h>

// Problem constants
constexpr int B = 8, N = 4096, D = 768;
constexpr int H = 12, K = 16, U = 4, V = 64, L = 23, PAD = 11;
constexpr int CQ = 192;           // q channels [0,192)
constexpr int CK = 64;            // k channels [192,256)
constexpr int CV = 256;           // v channels [256,512)
constexpr int CT = 512;           // total channels
constexpr int CV0 = CQ + CK;      // 256
constexpr float EPS = 1e-5f;

typedef _Float16 f16x8 __attribute__((ext_vector_type(8)));
typedef _Float16 f16x4 __attribute__((ext_vector_type(4)));
typedef float    f32x4 __attribute__((ext_vector_type(4)));

// ---------------------------------------------------------------------------
// K1: fused projection GEMM on MFMA (f16 inputs, fp32 accum, f16 output)
//   P[b][c][n] = sum_d W[c][d] * x[b][n][d]
//   128x128 tile, BK=32, 4 waves. Plain 3D grid (swizzle reverted: it gave
//   no FETCH reduction — L3 already absorbed re-reads — and cost ~35us).
//   Global loads for step t+1 issued AFTER the 2nd barrier so they overlap
//   ds_read+MFMA of step t (issue-early / write-late, G15).
// ---------------------------------------------------------------------------
__device__ __forceinline__ int lds_off(int row, int slot) {
    int p = slot ^ (row & 3) ^ ((row >> 2) & 3);
    return row * 64 + p * 16;          // byte offset
}

__device__ __forceinline__ f16x8 cvt8r(float4 a, float4 b) {
    f16x8 r;
    r[0] = (_Float16)a.x; r[1] = (_Float16)a.y; r[2] = (_Float16)a.z; r[3] = (_Float16)a.w;
    r[4] = (_Float16)b.x; r[5] = (_Float16)b.y; r[6] = (_Float16)b.z; r[7] = (_Float16)b.w;
    return r;
}

__global__ __launch_bounds__(256) void k_proj(
    const float* __restrict__ x,
    const float* __restrict__ Wq, const float* __restrict__ Wk,
    const float* __restrict__ Wv, _Float16* __restrict__ Ph)
{
    __shared__ _Float16 As[128 * 32];   // [row=c][col=d] swizzled
    __shared__ _Float16 Bs[128 * 32];   // [row=n][col=d] swizzled
    const int b  = blockIdx.z;
    const int bc = blockIdx.y * 128;
    const int bn = blockIdx.x * 128;
    const int tid  = threadIdx.x;
    const int lane = tid & 63;
    const int wave = tid >> 6;
    const int wr = wave >> 1, wc = wave & 1;

    // staging: thread t owns row t>>1, 16 f16 cols starting at (t&1)*16
    const int srow  = tid >> 1;
    const int scolg = (tid & 1) * 16;
    const int s0    = (tid & 1) * 2;
    const int c = bc + srow;
    const float* wrow;
    if (c < CQ)       wrow = Wq + (size_t)c * D;
    else if (c < CV0) wrow = Wk + (size_t)(c - CQ) * D;
    else              wrow = Wv + (size_t)(c - CV0) * D;
    const float* xrow = x + ((size_t)b * N + bn + srow) * D;

    const int fr = lane & 15;
    const int sl = lane >> 4;

    f32x4 acc[4][4] = {};

    // prologue: load step 0
    float4 w0 = *(const float4*)(wrow + scolg);
    float4 w1 = *(const float4*)(wrow + scolg + 4);
    float4 w2 = *(const float4*)(wrow + scolg + 8);
    float4 w3 = *(const float4*)(wrow + scolg + 12);
    float4 x0 = *(const float4*)(xrow + scolg);
    float4 x1 = *(const float4*)(xrow + scolg + 4);
    float4 x2 = *(const float4*)(xrow + scolg + 8);
    float4 x3 = *(const float4*)(xrow + scolg + 12);

    for (int kt = 0; kt < D; kt += 32) {
        __syncthreads();
        *(f16x8*)((char*)As + lds_off(srow, s0))     = cvt8r(w0, w1);
        *(f16x8*)((char*)As + lds_off(srow, s0 + 1)) = cvt8r(w2, w3);
        *(f16x8*)((char*)Bs + lds_off(srow, s0))     = cvt8r(x0, x1);
        *(f16x8*)((char*)Bs + lds_off(srow, s0 + 1)) = cvt8r(x2, x3);
        __syncthreads();

        if (kt + 32 < D) {   // issue next-step loads; overlap with compute
            const int o = kt + 32 + scolg;
            w0 = *(const float4*)(wrow + o);
            w1 = *(const float4*)(wrow + o + 4);
            w2 = *(const float4*)(wrow + o + 8);
            w3 = *(const float4*)(wrow + o + 12);
            x0 = *(const float4*)(xrow + o);
            x1 = *(const float4*)(xrow + o + 4);
            x2 = *(const float4*)(xrow + o + 8);
            x3 = *(const float4*)(xrow + o + 12);
        }

        f16x8 af[4], bfr[4];
        #pragma unroll
        for (int i = 0; i < 4; ++i) {
            af[i]  = *(const f16x8*)((char*)As + lds_off(wr * 64 + i * 16 + fr, sl));
            bfr[i] = *(const f16x8*)((char*)Bs + lds_off(wc * 64 + i * 16 + fr, sl));
        }
        #pragma unroll
        for (int mi = 0; mi < 4; ++mi)
            #pragma unroll
            for (int ni = 0; ni < 4; ++ni)
                acc[mi][ni] = __builtin_amdgcn_mfma_f32_16x16x32_f16(
                    af[mi], bfr[ni], acc[mi][ni], 0, 0, 0);
    }

    // epilogue: D layout col = lane&15, row = (lane>>4)*4 + reg; f16 store
    _Float16* Pb = Ph + ((size_t)b * CT + bc) * N + bn;
    #pragma unroll
    for (int mi = 0; mi < 4; ++mi)
        #pragma unroll
        for (int ni = 0; ni < 4; ++ni)
            #pragma unroll
            for (int r = 0; r < 4; ++r) {
                const int row = wr * 64 + mi * 16 + sl * 4 + r;
                const int col = wc * 64 + ni * 16 + fr;
                Pb[(size_t)row * N + col] = (_Float16)acc[mi][ni][r];
            }
}

// ---------------------------------------------------------------------------
// K2: BN stats -> per-channel scale/shift (q and v channels only), on f16 P
// ---------------------------------------------------------------------------
__global__ __launch_bounds__(256) void k_bnstats(
    const _Float16* __restrict__ Ph,
    const float* __restrict__ gq, const float* __restrict__ bq,
    const float* __restrict__ gv, const float* __restrict__ bv,
    float* __restrict__ sArr, float* __restrict__ tArr)
{
    const int ci = blockIdx.x;              // 0..447
    const int c  = (ci < CQ) ? ci : ci + CK;
    float g, be;
    if (ci < CQ) { g = gq[ci];      be = bq[ci]; }
    else         { g = gv[ci - CQ]; be = bv[ci - CQ]; }

    const int tid = threadIdx.x;
    float s = 0.f, s2 = 0.f;
    for (int b = 0; b < B; ++b) {
        const _Float16* row = Ph + ((size_t)b * CT + c) * N;
        #pragma unroll
        for (int i = 0; i < 2; ++i) {
            f16x8 v = ((const f16x8*)row)[i * 256 + tid];
            #pragma unroll
            for (int j = 0; j < 8; ++j) {
                float f = (float)v[j];
                s += f; s2 += f * f;
            }
        }
    }
    #pragma unroll
    for (int off = 32; off; off >>= 1) {
        s  += __shfl_xor(s, off);
        s2 += __shfl_xor(s2, off);
    }
    __shared__ float ls[4], ls2[4];
    if ((tid & 63) == 0) { ls[tid >> 6] = s; ls2[tid >> 6] = s2; }
    __syncthreads();
    if (tid == 0) {
        float S = ls[0] + ls[1] + ls[2] + ls[3];
        float S2 = ls2[0] + ls2[1] + ls2[2] + ls2[3];
        const float invM = 1.0f / (float)(B * N);
        float mean = S * invM;
        float var  = S2 * invM - mean * mean;
        float sc   = g / sqrtf(var + EPS);
        sArr[c] = sc;
        tArr[c] = be - mean * sc;
    }
}

// ---------------------------------------------------------------------------
// K3: softmax row stats for k channels: max and 1/sum(exp(x-max)) per (b,kc)
// ---------------------------------------------------------------------------
__global__ __launch_bounds__(256) void k_kstats(
    const _Float16* __restrict__ Ph, float* __restrict__ mxk, float* __restrict__ invk)
{
    const int b = blockIdx.y, kc = blockIdx.x;
    const _Float16* row = Ph + ((size_t)b * CT + CQ + kc) * N;
    const int tid = threadIdx.x;
    float v[16];
    float m = -3.4e38f;
    #pragma unroll
    for (int i = 0; i < 2; ++i) {
        f16x8 t = ((const f16x8*)row)[i * 256 + tid];
        #pragma unroll
        for (int j = 0; j < 8; ++j) {
            v[i*8+j] = (float)t[j];
            m = fmaxf(m, v[i*8+j]);
        }
    }
    #pragma unroll
    for (int off = 32; off; off >>= 1) m = fmaxf(m, __shfl_xor(m, off));
    __shared__ float rA[4], rB[4];
    if ((tid & 63) == 0) rA[tid >> 6] = m;
    __syncthreads();
    m = fmaxf(fmaxf(rA[0], rA[1]), fmaxf(rA[2], rA[3]));
    float s = 0.f;
    #pragma unroll
    for (int i = 0; i < 16; ++i) s += __expf(v[i] - m);
    #pragma unroll
    for (int off = 32; off; off >>= 1) s += __shfl_xor(s, off);
    if ((tid & 63) == 0) rB[tid >> 6] = s;
    __syncthreads();
    if (tid == 0) {
        s = rB[0] + rB[1] + rB[2] + rB[3];
        mxk[b * CK + kc]  = m;
        invk[b * CK + kc] = 1.f / s;
    }
}

// ---------------------------------------------------------------------------
// K3b: qT[b][n][ch] = f16( BN(P[b][ch][n]) ), ch < 192  (tiled transpose)
// ---------------------------------------------------------------------------
__global__ __launch_bounds__(256) void k_qt(
    const _Float16* __restrict__ Ph, const float* __restrict__ sArr,
    const float* __restrict__ tArr, _Float16* __restrict__ qT)
{
    __shared__ _Float16 tl[64][40];       // row stride 80B (16B multiple)
    const int b  = blockIdx.z;
    const int c0 = blockIdx.y * 32;
    const int n0 = blockIdx.x * 64;
    const int tid = threadIdx.x;

    const int ch = tid >> 3, seg = tid & 7;
    const int c = c0 + ch;
    f16x8 v = *(const f16x8*)(Ph + ((size_t)b * CT + c) * N + n0 + seg * 8);
    const float sc = sArr[c], tt = tArr[c];
    #pragma unroll
    for (int i = 0; i < 8; ++i)
        tl[seg * 8 + i][ch] = (_Float16)((float)v[i] * sc + tt);
    __syncthreads();

    const int n = tid >> 2, part = tid & 3;
    f16x8 o = *(const f16x8*)&tl[n][part * 8];
    *(f16x8*)(qT + ((size_t)b * N + n0 + n) * CQ + c0 + part * 8) = o;
}

// ---------------------------------------------------------------------------
// K4: zero lam_c
// ---------------------------------------------------------------------------
__global__ void k_zero(float* __restrict__ p)
{
    ((float4*)p)[blockIdx.x * 256 + threadIdx.x] = float4{0.f, 0.f, 0.f, 0.f};
}

// ---------------------------------------------------------------------------
// K5: lam_c[b][k][v] += sum_{u,n} softmax(k)[b][k*U+u][n] * bn(v)[b][v*U+u][n]
// ---------------------------------------------------------------------------
__global__ __launch_bounds__(256) void k_lamc(
    const _Float16* __restrict__ Ph, const float* __restrict__ mxk,
    const float* __restrict__ invk, const float* __restrict__ sArr,
    const float* __restrict__ tArr, float* __restrict__ lamC)
{
    __shared__ float Kt[128][20];   // [n][k]
    __shared__ float Vt[128][68];   // [n][v]
    const int b = blockIdx.z, u = blockIdx.y;
    const int chunk0 = blockIdx.x * 512;
    const int tid = threadIdx.x;
    const int vv = tid & 63, kg = tid >> 6;
    float acc[4] = {0.f, 0.f, 0.f, 0.f};

    for (int sc = 0; sc < 4; ++sc) {
        const int nbase = chunk0 + sc * 128;
        __syncthreads();
        for (int idx = tid; idx < 16 * 128; idx += 256) {
            int kk = idx >> 7, n = idx & 127;
            int kc = kk * U + u;
            float raw = (float)Ph[((size_t)b * CT + CQ + kc) * N + nbase + n];
            Kt[n][kk] = __expf(raw - mxk[b * CK + kc]) * invk[b * CK + kc];
        }
        for (int idx = tid; idx < 64 * 128; idx += 256) {
            int vvv = idx >> 7, n = idx & 127;
            int c = CV0 + vvv * U + u;
            float raw = (float)Ph[((size_t)b * CT + c) * N + nbase + n];
            Vt[n][vvv] = raw * sArr[c] + tArr[c];
        }
        __syncthreads();
        #pragma unroll 4
        for (int n = 0; n < 128; ++n) {
            float4 kv = *(const float4*)&Kt[n][kg * 4];
            float vx = Vt[n][vv];
            acc[0] += kv.x * vx; acc[1] += kv.y * vx;
            acc[2] += kv.z * vx; acc[3] += kv.w * vx;
        }
    }
    #pragma unroll
    for (int j = 0; j < 4; ++j)
        atomicAdd(&lamC[((size_t)b * K + kg * 4 + j) * V + vv], acc[j]);
}

// ---------------------------------------------------------------------------
// K6: fused conv + output, MFMA formulation (unchanged structure; f16 P)
// ---------------------------------------------------------------------------
__global__ __launch_bounds__(512, 4) void k_out(
    const _Float16* __restrict__ Ph, const float* __restrict__ rel,
    const float* __restrict__ lamC, const float* __restrict__ sArr,
    const float* __restrict__ tArr, const _Float16* __restrict__ qT,
    float* __restrict__ Y)
{
    constexpr int NT = 32;
    constexpr int VST = 72;                  // np stride (f16), mult of 8
    __shared__ _Float16 vsegT[256 * VST];    // [u*64+v][np]  (np 0..55 used)
    __shared__ _Float16 relS[8 * 4 * 16 * 32]; // [d][u][k][j]

    const int b  = blockIdx.y;
    const int n0 = blockIdx.x * NT;
    const int tid  = threadIdx.x;
    const int lane = tid & 63;
    const int wave = tid >> 6;
    const int fr = lane & 15;   // k row / v col / h row
    const int sl = lane >> 4;   // slot 0..3

    // --- stage vsegT: wave w -> channels w*32..w*32+31, lane = np
    for (int i = 0; i < 32; ++i) {
        const int ch  = wave * 32 + i;            // = v*4+u
        const int c   = CV0 + ch;
        const int row = (ch & 3) * 64 + (ch >> 2);
        const int n   = n0 - PAD + lane;
        float val = 0.f;
        if (lane < 54 && n >= 0 && n < N)
            val = (float)Ph[((size_t)b * CT + c) * N + n] * sArr[c] + tArr[c];
        if (lane < 56)
            vsegT[row * VST + lane] = (_Float16)val;
    }
    // --- stage shifted rel: relS[d][u][k][j] = rel[k][u][j-d] (0 outside)
    for (int idx = tid; idx < 8 * 4 * 16 * 32; idx += 512) {
        const int jj = idx & 31, kk = (idx >> 5) & 15;
        const int uu = (idx >> 9) & 3, dd = idx >> 11;
        const int l = jj - dd;
        float vv = (l >= 0 && l < L) ? rel[(kk * U + uu) * L + l] : 0.f;
        relS[idx] = (_Float16)vv;
    }
    // --- lamC fragment (C-layout): row k = sl*4+r, col v = vg*16+fr
    const int vg = wave & 3;
    const int nb = (wave >> 2) * 16;
    float lc[4];
    #pragma unroll
    for (int r = 0; r < 4; ++r)
        lc[r] = lamC[(size_t)b * K * V + (sl * 4 + r) * V + vg * 16 + fr];
    __syncthreads();

    const _Float16* qTb = qT + (size_t)b * N * CQ;

    for (int dlt = 0; dlt < 8; ++dlt) {
        f16x8 aU[4];
        #pragma unroll
        for (int u = 0; u < 4; ++u)
            aU[u] = *(const f16x8*)(relS + ((dlt * 4 + u) * 16 + fr) * 32 + sl * 8);
        #pragma unroll
        for (int rep = 0; rep < 2; ++rep) {
            const int A  = nb + rep * 8;
            const int nn = A + dlt;
            f32x4 acc = {lc[0], lc[1], lc[2], lc[3]};
            #pragma unroll
            for (int u = 0; u < 4; ++u) {
                f16x8 bf = *(const f16x8*)(vsegT + (u * 64 + vg * 16 + fr) * VST + A + sl * 8);
                acc = __builtin_amdgcn_mfma_f32_16x16x32_f16(aU[u], bf, acc, 0, 0, 0);
            }
            f16x4 lam16;
            #pragma unroll
            for (int r = 0; r < 4; ++r) lam16[r] = (_Float16)acc[r];
            f16x4 q4 = *(const f16x4*)(qTb + (size_t)(n0 + nn) * CQ + fr * 16 + sl * 4);
            f32x4 y = {0.f, 0.f, 0.f, 0.f};
            y = __builtin_amdgcn_mfma_f32_16x16x16f16(q4, lam16, y, 0, 0, 0);
            if (sl < 3) {
                float* yr = Y + ((size_t)b * N + n0 + nn) * (H * V) + vg * 16 + fr;
                #pragma unroll
                for (int r = 0; r < 4; ++r)
                    yr[(sl * 4 + r) * 64] = y[r];
            }
        }
    }
}

// ---------------------------------------------------------------------------
extern "C" void kernel_launch(void* const* d_in, const int* in_sizes, int n_in,
                              void* d_out, int out_size, void* d_ws, size_t ws_size,
                              hipStream_t stream)
{
    const float* x   = (const float*)d_in[0];
    const float* Wq  = (const float*)d_in[1];
    const float* Wk  = (const float*)d_in[2];
    const float* Wv  = (const float*)d_in[3];
    const float* gq  = (const float*)d_in[4];
    const float* bq  = (const float*)d_in[5];
    const float* gv  = (const float*)d_in[6];
    const float* bv  = (const float*)d_in[7];
    const float* rel = (const float*)d_in[8];
    float* Y = (float*)d_out;

    _Float16* Ph  = (_Float16*)d_ws;                  // B*CT*N f16 (32 MiB)
    float* sArr = (float*)(Ph + (size_t)B * CT * N);  // CT
    float* tArr = sArr + CT;                          // CT
    float* lamC = tArr + CT;                          // B*K*V = 8192
    float* mxk  = lamC + (size_t)B * K * V;           // B*CK
    float* invk = mxk + B * CK;                       // B*CK
    _Float16* qT = (_Float16*)(invk + B * CK);        // B*N*CQ f16 (12.6 MB)

    k_proj   <<<dim3(N / 128, CT / 128, B), 256, 0, stream>>>(x, Wq, Wk, Wv, Ph);
    k_bnstats<<<dim3(CQ + CV), 256, 0, stream>>>(Ph, gq, bq, gv, bv, sArr, tArr);
    k_kstats <<<dim3(CK, B), 256, 0, stream>>>(Ph, mxk, invk);
    k_qt     <<<dim3(N / 64, CQ / 32, B), 256, 0, stream>>>(Ph, sArr, tArr, qT);
    k_zero   <<<dim3(8), 256, 0, stream>>>(lamC);
    k_lamc   <<<dim3(N / 512, U, B), 256, 0, stream>>>(Ph, mxk, invk, sArr, tArr, lamC);
    k_out    <<<dim3(N / 32, B), 512, 0, stream>>>(Ph, rel, lamC, sArr, tArr, qT, Y);
}